// Round 1
// baseline (399.834 us; speedup 1.0000x reference)
//
#include <hip/hip_runtime.h>

typedef __attribute__((ext_vector_type(8))) short short8_t;
typedef __attribute__((ext_vector_type(4))) float f32x4;

#define MASK_VAL (-4294967295.0f)

__device__ __forceinline__ short f2bf(float x) {
    unsigned u;
    __builtin_memcpy(&u, &x, 4);
    u += 0x7FFFu + ((u >> 16) & 1u);   // round-to-nearest-even
    return (short)(u >> 16);
}
__device__ __forceinline__ float bf2f(short s) {
    unsigned u = ((unsigned)(unsigned short)s) << 16;
    float f;
    __builtin_memcpy(&f, &u, 4);
    return f;
}

// One block per batch element b.
// h1[t,h] = relu( sum_i k[t,i] * V[i,h] + c[h] )
//   where V[i,h] = W1[64+i,h] - W1[128+i,h] + q[i]*W1[192+i,h]
//         c[h]   = b1[h] + sum_i q[i]*(W1[i,h] + W1[128+i,h])
// h2[t,o] = relu( h1[t,:] @ W2[:,o] + b2[o] );  s[t] = h2[t,:] @ W3 + b3
// softmax over masked s, then out = sum_t w[t] * k[t,:]
__global__ __launch_bounds__(256, 2) void attn_pool_kernel(
    const float* __restrict__ query,    // (B,1,64)
    const float* __restrict__ keys,     // (B,200,64)
    const int*   __restrict__ keys_len, // (B,1)
    const float* __restrict__ W1,       // (256,64)
    const float* __restrict__ b1,       // (64)
    const float* __restrict__ W2,       // (64,32)
    const float* __restrict__ b2,       // (32)
    const float* __restrict__ W3,       // (32,1)
    const float* __restrict__ b3,       // (1)
    float* __restrict__ out)            // (B,1,64)
{
    constexpr int T = 200, TP = 208, E = 64, H1 = 64, H2 = 32, STR = 72;
    __shared__ short Ks [TP * STR];   // keys bf16, A-frag friendly (row-major, pad 72)
    __shared__ short h1s[TP * STR];   // h1 bf16
    __shared__ short Vs [E  * STR];   // Vs[h][i] = V[i][h]  (B-operand: transposed)
    __shared__ short W2s[H2 * STR];   // W2s[o][h] = W2[h][o]
    __shared__ float qs[E];
    __shared__ float cs[H1];
    __shared__ float b2s[H2];
    __shared__ float w3s[H2];
    __shared__ float s_arr[TP];
    __shared__ float wsm[TP];
    __shared__ float red[256];
    __shared__ float red4a[4], red4b[4];

    const int b    = blockIdx.x;
    const int tid  = threadIdx.x;
    const int lane = tid & 63;
    const int wid  = tid >> 6;
    const int col  = lane & 15;
    const int quad = lane >> 4;

    // ---- stage q, zero K tail rows, stage small vectors ----
    if (tid < 16) {
        ((float4*)qs)[tid] = ((const float4*)(query + (size_t)b * E))[tid];
    }
    for (int i = tid; i < (TP - T) * STR; i += 256) Ks[T * STR + i] = 0;
    if (tid < H2) { b2s[tid] = b2[tid]; w3s[tid] = W3[tid]; }
    __syncthreads();

    // ---- stage keys -> bf16 LDS (coalesced float4 loads) ----
    {
        const float* kb = keys + (size_t)b * (T * E);
        for (int f = tid * 4; f < T * E; f += 256 * 4) {
            float4 v = *(const float4*)(kb + f);
            int t = f >> 6, e = f & 63;
            short4 s4;
            s4.x = f2bf(v.x); s4.y = f2bf(v.y); s4.z = f2bf(v.z); s4.w = f2bf(v.w);
            *(short4*)&Ks[t * STR + e] = s4;
        }
    }
    // ---- fold V_b (coalesced over h across threads) ----
    {
        int h = tid & 63, i0 = tid >> 6;
        for (int j = 0; j < 16; ++j) {
            int i = i0 + j * 4;
            float v = W1[(64 + i) * 64 + h] - W1[(128 + i) * 64 + h]
                    + qs[i] * W1[(192 + i) * 64 + h];
            Vs[h * STR + i] = f2bf(v);
        }
    }
    // ---- c_b ----
    if (tid < H1) {
        float acc = b1[tid];
        for (int i = 0; i < E; ++i)
            acc += qs[i] * (W1[i * 64 + tid] + W1[(128 + i) * 64 + tid]);
        cs[tid] = acc;
    }
    // ---- W2 transposed to LDS bf16 ----
    {
        int o = tid & 31, h0 = tid >> 5;
        for (int j = 0; j < 8; ++j) {
            int h = h0 + j * 8;
            W2s[o * STR + h] = f2bf(W2[h * 32 + o]);
        }
    }
    __syncthreads();

    // ---- GEMM1: h1 = relu(K @ V + c), 13 M-tiles x 4 N-tiles, K=64 (2 steps) ----
    for (int mt = wid; mt < 13; mt += 4) {
        f32x4 acc[4] = {f32x4{0,0,0,0}, f32x4{0,0,0,0}, f32x4{0,0,0,0}, f32x4{0,0,0,0}};
        for (int ks = 0; ks < 2; ++ks) {
            short8_t a = *(const short8_t*)&Ks[(mt * 16 + col) * STR + ks * 32 + quad * 8];
            for (int nt = 0; nt < 4; ++nt) {
                short8_t bb = *(const short8_t*)&Vs[(nt * 16 + col) * STR + ks * 32 + quad * 8];
                acc[nt] = __builtin_amdgcn_mfma_f32_16x16x32_bf16(a, bb, acc[nt], 0, 0, 0);
            }
        }
        for (int nt = 0; nt < 4; ++nt) {
            float cadd = cs[nt * 16 + col];
            for (int r = 0; r < 4; ++r) {
                int t = mt * 16 + quad * 4 + r;
                float v = fmaxf(acc[nt][r] + cadd, 0.0f);
                h1s[t * STR + nt * 16 + col] = f2bf(v);
            }
        }
    }
    __syncthreads();

    // ---- GEMM2 + fused b2/relu/W3/b3 -> s[t] ----
    float b3v = b3[0];
    for (int mt = wid; mt < 13; mt += 4) {
        f32x4 acc[2] = {f32x4{0,0,0,0}, f32x4{0,0,0,0}};
        for (int ks = 0; ks < 2; ++ks) {
            short8_t a = *(const short8_t*)&h1s[(mt * 16 + col) * STR + ks * 32 + quad * 8];
            for (int nt = 0; nt < 2; ++nt) {
                short8_t bb = *(const short8_t*)&W2s[(nt * 16 + col) * STR + ks * 32 + quad * 8];
                acc[nt] = __builtin_amdgcn_mfma_f32_16x16x32_bf16(a, bb, acc[nt], 0, 0, 0);
            }
        }
        for (int r = 0; r < 4; ++r) {
            float v = fmaxf(acc[0][r] + b2s[col], 0.0f) * w3s[col]
                    + fmaxf(acc[1][r] + b2s[16 + col], 0.0f) * w3s[16 + col];
            v += __shfl_xor(v, 1);
            v += __shfl_xor(v, 2);
            v += __shfl_xor(v, 4);
            v += __shfl_xor(v, 8);
            if (col == 0) s_arr[mt * 16 + quad * 4 + r] = v + b3v;
        }
    }
    __syncthreads();

    // ---- masked softmax over t (reference semantics incl. len==0 -> uniform) ----
    int len = keys_len[b];
    float val = (tid < T) ? ((tid < len) ? s_arr[tid] : MASK_VAL) : -INFINITY;
    float m = val;
    for (int off = 32; off >= 1; off >>= 1) m = fmaxf(m, __shfl_xor(m, off));
    if (lane == 0) red4a[wid] = m;
    __syncthreads();
    m = fmaxf(fmaxf(red4a[0], red4a[1]), fmaxf(red4a[2], red4a[3]));
    float p = (tid < T) ? __expf(val - m) : 0.0f;
    float s = p;
    for (int off = 32; off >= 1; off >>= 1) s += __shfl_xor(s, off);
    if (lane == 0) red4b[wid] = s;
    __syncthreads();
    float S = red4b[0] + red4b[1] + red4b[2] + red4b[3];
    if (tid < T) wsm[tid] = p / S;
    __syncthreads();

    // ---- out[e] = sum_t w[t] * k[t,e] ----
    {
        int e = tid & 63, g = tid >> 6;
        float acc = 0.0f;
        for (int t = g; t < T; t += 4)
            acc += wsm[t] * bf2f(Ks[t * STR + e]);
        red[g * 64 + e] = acc;
        __syncthreads();
        if (tid < 64)
            out[(size_t)b * E + tid] = red[tid] + red[64 + tid] + red[128 + tid] + red[192 + tid];
    }
}

extern "C" void kernel_launch(void* const* d_in, const int* in_sizes, int n_in,
                              void* d_out, int out_size, void* d_ws, size_t ws_size,
                              hipStream_t stream) {
    const float* query    = (const float*)d_in[0];
    const float* keys     = (const float*)d_in[1];
    const int*   keys_len = (const int*)d_in[2];
    const float* W1       = (const float*)d_in[3];
    const float* b1       = (const float*)d_in[4];
    const float* W2       = (const float*)d_in[5];
    const float* b2       = (const float*)d_in[6];
    const float* W3       = (const float*)d_in[7];
    const float* b3       = (const float*)d_in[8];
    float* out            = (float*)d_out;

    const int B = in_sizes[2];  // 4096 (keys_len has B*1 elements)

    attn_pool_kernel<<<dim3(B), dim3(256), 0, stream>>>(
        query, keys, keys_len, W1, b1, W2, b2, W3, b3, out);
}